// Round 15
// baseline (249.056 us; speedup 1.0000x reference)
//
#include <hip/hip_runtime.h>
#include <math.h>

#define B_ 8
#define C_ 64
#define H_ 192
#define W_ 192
#define HW_ (H_*W_)

typedef __attribute__((ext_vector_type(8))) short bf16x8;
typedef __attribute__((ext_vector_type(4))) float f32x4;
typedef __attribute__((ext_vector_type(4))) unsigned short u16x4;
typedef __attribute__((ext_vector_type(8))) unsigned short u16x8;
typedef __attribute__((ext_vector_type(4))) unsigned int u32x4;

__device__ __forceinline__ float lk(float v){ return v >= 0.f ? v : 0.1f*v; }
__device__ __forceinline__ float bf2f(unsigned short h){ return __uint_as_float(((unsigned)h)<<16); }
__device__ __forceinline__ unsigned short f2bf(float f){
    unsigned u = __float_as_uint(f);
    return (unsigned short)((u + 0x7fffu + ((u>>16)&1u)) >> 16);
}
__device__ __forceinline__ f32x4 mfma16(bf16x8 a, bf16x8 b, f32x4 c){
    return __builtin_amdgcn_mfma_f32_16x16x32_bf16(a, b, c, 0, 0, 0);
}

// XCD z-major decompose: L%8 = image = XCD; tiles sweep row-major within image.
__device__ __forceinline__ void xcd_decomp(int L, int& b, int& h0, int& w0){
    b = L & 7;
    int t = L >> 3;
    h0 = (t / 12) * 16;
    w0 = (t % 12) * 16;
}

// LDS staging pad: 11 full wave-rounds of 256 thr x 16B = 45056 B (2816 granules)
#define XS_ELEMS 22528
#define TSTRIDE 260   // xprep pivot row stride (u16): 520B row -> 2-dword bank step (free)

// ---------------------------------------------------------------- merged prep:
// blocks 0..1151  : x fp32 NCHW -> bf16 NHWC (vectorized LDS pivot)
// blocks 1152..1159: per-image hypernet (kern/att/addm)
// blocks 1160..1383: weight repack + cw cast + zero page
__global__ __launch_bounds__(256) void k_prep(
    const float* __restrict__ xf, unsigned short* __restrict__ xb,
    const float* __restrict__ d,
    const float* __restrict__ kw1a, const float* __restrict__ kw2a,
    const float* __restrict__ ca1a, const float* __restrict__ ca2a,
    const float* __restrict__ kw1b, const float* __restrict__ kw2b,
    const float* __restrict__ ca1b, const float* __restrict__ ca2b,
    const float* __restrict__ aw1,  const float* __restrict__ aw2,
    float* __restrict__ kern1, float* __restrict__ att1,
    float* __restrict__ kern2, float* __restrict__ att2,
    float* __restrict__ addm,
    const float* __restrict__ w1, const float* __restrict__ w2, const float* __restrict__ w3,
    const float* __restrict__ cw1, const float* __restrict__ cw2,
    unsigned short* __restrict__ wA1, unsigned short* __restrict__ wA2, unsigned short* __restrict__ wA3,
    unsigned short* __restrict__ cwA1, unsigned short* __restrict__ cwA2,
    unsigned short* __restrict__ zp)
{
    int blk = blockIdx.x, tid = threadIdx.x;
    if (blk < 1152){
        // ---- xprep: vectorized float4 reads -> LDS pivot -> coalesced NHWC granule stores
        int b = blk & 7, px0 = (blk >> 3)*256;
        __shared__ unsigned short ts[64*TSTRIDE];   // [c][px], stride 260
        int c = tid & 63, q4 = tid >> 6;            // lanes sweep c -> conflict-free writes
        const float* src = xf + ((size_t)(b*64 + c))*HW_ + px0 + q4*64;
        #pragma unroll
        for (int k=0; k<16; k++){
            f32x4 v = *(const f32x4*)(src + k*4);
            u16x4 o;
            #pragma unroll
            for (int j=0; j<4; j++) o[j] = f2bf(v[j]);
            *(u16x4*)&ts[c*TSTRIDE + q4*64 + k*4] = o;
        }
        __syncthreads();
        int kg = tid & 7, pg = tid >> 3;
        #pragma unroll
        for (int jj=0; jj<8; jj++){
            int px = pg + 32*jj;
            u16x8 o;
            #pragma unroll
            for (int i=0; i<8; i++) o[i] = ts[(kg*8+i)*TSTRIDE + px];
            *(u16x8*)&xb[((size_t)(b*HW_) + px0 + px)*64 + kg*8] = o;
        }
    } else if (blk < 1160){
        // ---- hypernet for image b
        int b = blk - 1152;
        __shared__ float sd[64], sv[64], su[8];
        if (tid < 64) sd[tid] = d[b*64 + tid];
        __syncthreads();
        if (tid < 64){ float s=0.f; for(int k=0;k<64;k++) s += sd[k]*kw1a[tid*64+k]; sv[tid]=lk(s); }
        if (tid >= 64 && tid < 72){ int r=tid-64; float s=0.f; for(int k=0;k<64;k++) s += sd[k]*ca1a[r*64+k]; su[r]=lk(s); }
        __syncthreads();
        for (int i=tid;i<576;i+=256){ float s=0.f; for(int j=0;j<64;j++) s += sv[j]*kw2a[i*64+j]; kern1[b*576+i]=s; }
        if (tid < 64){ float s=0.f; for(int r=0;r<8;r++) s += su[r]*ca2a[tid*8+r]; att1[b*64+tid]=1.f/(1.f+expf(-s)); }
        __syncthreads();
        if (tid < 64){ float s=0.f; for(int k=0;k<64;k++) s += sd[k]*kw1b[tid*64+k]; sv[tid]=lk(s); }
        if (tid >= 64 && tid < 72){ int r=tid-64; float s=0.f; for(int k=0;k<64;k++) s += sd[k]*ca1b[r*64+k]; su[r]=lk(s); }
        __syncthreads();
        for (int i=tid;i<576;i+=256){ float s=0.f; for(int j=0;j<64;j++) s += sv[j]*kw2b[i*64+j]; kern2[b*576+i]=s; }
        if (tid < 64){ float s=0.f; for(int r=0;r<8;r++) s += su[r]*ca2b[tid*8+r]; att2[b*64+tid]=1.f/(1.f+expf(-s)); }
        __syncthreads();
        if (tid < 64){ float s=0.f; for(int k=0;k<64;k++) s += sd[k]*aw1[tid*64+k]; sv[tid]=lk(s); }
        __syncthreads();
        for (int i=tid;i<1024;i+=256){ float s=0.f; for(int j=0;j<64;j++) s += sv[j]*aw2[i*64+j]; addm[b*1024+i]=s; }
    } else {
        int pb = blk - 1160;
        if (pb < 192){
            const float* w = (pb < 64) ? w1 : (pb < 128) ? w2 : w3;
            unsigned short* wA = (pb < 64) ? wA1 : (pb < 128) ? wA2 : wA3;
            int oc = pb & 63;
            for (int i = tid; i < 576; i += 256){
                int t = i >> 6, ic = i & 63;
                wA[oc*576 + i] = f2bf(w[oc*576 + ic*9 + t]);
            }
        } else {
            int i = (pb - 192)*256 + tid;
            if (i < 4096) cwA1[i] = f2bf(cw1[i]);
            else          cwA2[i-4096] = f2bf(cw2[i-4096]);
            if (blk == 1383 && tid < 32) zp[tid] = 0;
        }
    }
}

// ---------------------------------------------------------------- DMA staging: linear LDS dest + pre-swizzled source
// LDS slot e holds global granule j = (e&7) ^ ((e>>3)&7) of pixel e>>3; readers
// use xs[pix*64 + ((gran ^ (pix&7))*8)] (involution).
__device__ __forceinline__ void stage_gl(const unsigned short* __restrict__ in,
                                         unsigned short* xs,
                                         const unsigned short* __restrict__ zp,
                                         int b, int h0, int w0, int wv, int lane)
{
    #pragma unroll
    for (int i=0; i<11; i++){
        int e = i*256 + wv*64 + lane;
        int pix = e >> 3;
        int j = (e & 7) ^ (pix & 7);
        int r = pix/18, col = pix - r*18;
        int gh = h0 - 1 + r, gw = w0 - 1 + col;
        const unsigned short* src = (gh >= 0 && gh < H_ && gw >= 0 && gw < W_)
            ? &in[((size_t)(b*HW_ + gh*W_ + gw))*64 + j*8] : zp;
        __builtin_amdgcn_global_load_lds(
            (const __attribute__((address_space(1))) void*)src,
            (__attribute__((address_space(3))) void*)&xs[(size_t)(i*256 + wv*64)*8],
            16, 0, 0);
    }
}

// ---------------------------------------------------------------- main MFMA loop (R4/R8/R11-measured structure)
__device__ __forceinline__ void conv_main(const unsigned short* xs,
                                          const unsigned short* __restrict__ wbase,
                                          bf16x8 afr[2][2],
                                          int n, int g, int rowbase, f32x4 acc[2][8])
{
    #pragma unroll 1
    for (int t=0; t<9; t++){
        bf16x8 nxt[2][2];
        if (t < 8){
            #pragma unroll
            for (int mf=0; mf<2; mf++)
                #pragma unroll
                for (int kf=0; kf<2; kf++)
                    nxt[mf][kf] = *(const bf16x8*)(wbase + mf*(16*576) + (t+1)*64 + kf*32);
        }
        int dy = t/3, dx = t - dy*3;
        #pragma unroll
        for (int r=0; r<8; r++){
            int pix = (rowbase + r + dy)*18 + (n + dx);
            int sw = pix & 7;
            #pragma unroll
            for (int kf=0; kf<2; kf++){
                bf16x8 bfr = *(const bf16x8*)&xs[pix*64 + (((kf*4+g) ^ sw)*8)];
                acc[0][r] = mfma16(afr[0][kf], bfr, acc[0][r]);
                acc[1][r] = mfma16(afr[1][kf], bfr, acc[1][r]);
            }
        }
        if (t < 8){
            #pragma unroll
            for (int mf=0; mf<2; mf++)
                #pragma unroll
                for (int kf=0; kf<2; kf++) afr[mf][kf] = nxt[mf][kf];
        }
    }
}

// ---------------------------------------------------------------- conv stages 1/2 (bf16 NHWC out)
template<int MODE>
__global__ __launch_bounds__(256) void k_conv(
    const unsigned short* __restrict__ in,
    const unsigned short* __restrict__ wA,
    const float* __restrict__ bias,
    const float* __restrict__ addm,
    const unsigned short* __restrict__ zp,
    unsigned short* __restrict__ outb)
{
    int b, h0, w0; xcd_decomp(blockIdx.x, b, h0, w0);
    int tid = threadIdx.x;
    __shared__ unsigned short xs[XS_ELEMS];

    int lane = tid & 63, wv = tid >> 6;
    int n = lane & 15, g = lane >> 4;
    int ochalf = (wv & 1)*32, rowbase = (wv >> 1)*8;

    stage_gl(in, xs, zp, b, h0, w0, wv, lane);

    const unsigned short* wbase = wA + (size_t)(ochalf + n)*576 + g*8;
    bf16x8 afr[2][2];
    #pragma unroll
    for (int mf=0; mf<2; mf++)
        #pragma unroll
        for (int kf=0; kf<2; kf++)
            afr[mf][kf] = *(const bf16x8*)(wbase + mf*(16*576) + kf*32);

    __syncthreads();

    f32x4 acc[2][8];
    f32x4 zz = {0.f,0.f,0.f,0.f};
    #pragma unroll
    for (int mf=0; mf<2; mf++)
        #pragma unroll
        for (int r=0; r<8; r++) acc[mf][r] = zz;

    conv_main(xs, wbase, afr, n, g, rowbase, acc);

    #pragma unroll
    for (int r=0; r<8; r++){
        int h = h0 + rowbase + r, w = w0 + n;
        float addv = 0.f;
        if (MODE == 0) addv = addm[b*1024 + (h/6)*32 + (w/6)];
        #pragma unroll
        for (int mf=0; mf<2; mf++){
            int oc0 = ochalf + mf*16 + g*4;
            f32x4 v = acc[mf][r];
            f32x4 b4 = *(const f32x4*)&bias[oc0];
            u16x4 o;
            #pragma unroll
            for (int j=0;j<4;j++){
                float val = v[j] + b4[j];
                if (MODE == 0) val = lk(val) + addv;
                o[j] = f2bf(val);
            }
            *(u16x4*)&outb[((size_t)(b*HW_ + h*W_ + w))*64 + oc0] = o;
        }
    }
}

// ---------------------------------------------------------------- conv3: bf16 residual (prefetched), pivot epilogue
__global__ __launch_bounds__(256) void kc3(
    const unsigned short* __restrict__ in,
    const unsigned short* __restrict__ wA,
    const float* __restrict__ bias,
    const unsigned short* __restrict__ xresb,
    const unsigned short* __restrict__ zp,
    float* __restrict__ outf)
{
    int b, h0, w0; xcd_decomp(blockIdx.x, b, h0, w0);
    int tid = threadIdx.x;
    __shared__ unsigned short xs[XS_ELEMS];   // reused as ys[64][256] after compute

    int lane = tid & 63, wv = tid >> 6;
    int n = lane & 15, g = lane >> 4;
    int ochalf = (wv & 1)*32, rowbase = (wv >> 1)*8;

    stage_gl(in, xs, zp, b, h0, w0, wv, lane);

    const unsigned short* wbase = wA + (size_t)(ochalf + n)*576 + g*8;
    bf16x8 afr[2][2];
    #pragma unroll
    for (int mf=0; mf<2; mf++)
        #pragma unroll
        for (int kf=0; kf<2; kf++)
            afr[mf][kf] = *(const bf16x8*)(wbase + mf*(16*576) + kf*32);

    // prefetch residual (independent of LDS): flies under the barrier + conv
    u16x4 xr[2][4];
    u16x4 xr2[2][4];
    #pragma unroll
    for (int mf=0; mf<2; mf++){
        int oc0 = ochalf + mf*16 + g*4;
        #pragma unroll
        for (int r=0; r<4; r++){
            int h = h0 + rowbase + r, w = w0 + n;
            xr[mf][r] = *(const u16x4*)&xresb[((size_t)(b*HW_ + h*W_ + w))*64 + oc0];
        }
        #pragma unroll
        for (int r=4; r<8; r++){
            int h = h0 + rowbase + r, w = w0 + n;
            xr2[mf][r-4] = *(const u16x4*)&xresb[((size_t)(b*HW_ + h*W_ + w))*64 + oc0];
        }
    }

    __syncthreads();

    f32x4 acc[2][8];
    f32x4 zz = {0.f,0.f,0.f,0.f};
    #pragma unroll
    for (int mf=0; mf<2; mf++)
        #pragma unroll
        for (int r=0; r<8; r++) acc[mf][r] = zz;

    conv_main(xs, wbase, afr, n, g, rowbase, acc);

    __syncthreads();   // all xs reads done; reuse as ys
    unsigned short* ys = xs;

    #pragma unroll
    for (int mf=0; mf<2; mf++){
        int oc0 = ochalf + mf*16 + g*4;
        int sw = ((oc0 >> 2) & 3) << 2;
        f32x4 b4 = *(const f32x4*)&bias[oc0];
        #pragma unroll
        for (int r=0; r<8; r++){
            int px = (rowbase + r)*16 + n;
            u16x4 xv = (r < 4) ? xr[mf][r] : xr2[mf][r-4];
            f32x4 v = acc[mf][r];
            #pragma unroll
            for (int j=0; j<4; j++)
                ys[(oc0 + j)*256 + (px ^ sw)] = f2bf(v[j] + b4[j] + bf2f(xv[j]));
        }
    }
    __syncthreads();

    int q = lane & 3, rr = lane >> 2;
    #pragma unroll 1
    for (int pass=0; pass<16; pass++){
        int oc = wv + pass*4;
        int sw = ((oc >> 2) & 3) << 2;
        int px = (rr*16 + q*4) ^ sw;
        u16x4 t = *(const u16x4*)&ys[oc*256 + px];
        size_t gidx = ((size_t)(b*C_ + oc))*HW_ + (size_t)(h0 + rr)*W_ + w0 + q*4;
        f32x4 o;
        #pragma unroll
        for (int j=0; j<4; j++) o[j] = bf2f(t[j]);
        *(f32x4*)&outf[gidx] = o;
    }
}

// ---------------------------------------------------------------- depthwise pass: 4 output rows, one 8-ch granule
__device__ __forceinline__ void dw_pass(const unsigned short* xs, const float* skT,
                                        int r0, int cc, int gg, bf16x8 pbv[4])
{
    float acc[4][8];
    #pragma unroll
    for (int k=0;k<4;k++)
        #pragma unroll
        for (int i=0;i<8;i++) acc[k][i] = 0.f;

    #pragma unroll
    for (int ir=0; ir<6; ir++){
        float f[3][8];
        #pragma unroll
        for (int dx=0; dx<3; dx++){
            int spix = (r0+ir)*18 + cc + dx;
            bf16x8 v = *(const bf16x8*)&xs[spix*64 + ((gg ^ (spix&7))*8)];
            #pragma unroll
            for (int i=0;i<8;i++) f[dx][i] = bf2f((unsigned short)v[i]);
        }
        #pragma unroll
        for (int k=0;k<4;k++){
            if (ir >= k && ir <= k+2){
                int dy = ir - k;
                #pragma unroll
                for (int dx=0; dx<3; dx++){
                    f32x4 ka = *(const f32x4*)&skT[(dy*3+dx)*64 + gg*8];
                    f32x4 kb = *(const f32x4*)&skT[(dy*3+dx)*64 + gg*8 + 4];
                    #pragma unroll
                    for (int i=0;i<4;i++){
                        acc[k][i]   = fmaf(f[dx][i],   ka[i], acc[k][i]);
                        acc[k][i+4] = fmaf(f[dx][i+4], kb[i], acc[k][i+4]);
                    }
                }
            }
        }
    }
    #pragma unroll
    for (int k=0;k<4;k++){
        bf16x8 pb;
        #pragma unroll
        for (int i=0;i<8;i++) pb[i] = (short)f2bf(lk(acc[k][i]));
        pbv[k] = pb;
    }
}

// ---------------------------------------------------------------- da_conv: 16x16 tile, dw->regs->MFMA mix
__global__ __launch_bounds__(256) void k_da(
    const unsigned short* __restrict__ xb,
    const float* __restrict__ kern,
    const float* __restrict__ att,
    const unsigned short* __restrict__ cwA,
    const float* __restrict__ cb,
    const unsigned short* __restrict__ zp,
    unsigned short* __restrict__ outb)
{
    int b, h0, w0; xcd_decomp(blockIdx.x, b, h0, w0);
    int tid = threadIdx.x;
    __shared__ unsigned short xs[XS_ELEMS];
    __shared__ float skernT[576];

    int lane = tid & 63, wv = tid >> 6;
    int cc = lane & 15, g = lane >> 4;
    int r0 = wv*4;

    stage_gl(xb, xs, zp, b, h0, w0, wv, lane);

    for (int i = tid; i < 576; i += 256)
        skernT[i] = kern[b*576 + (i & 63)*9 + (i >> 6)];

    bf16x8 afr[4][2];
    #pragma unroll
    for (int mf=0; mf<4; mf++)
        #pragma unroll
        for (int kf=0; kf<2; kf++)
            afr[mf][kf] = *(const bf16x8*)&cwA[(size_t)(mf*16 + cc)*64 + kf*32 + g*8];

    __syncthreads();

    f32x4 accm[4][4];
    f32x4 zz = {0.f,0.f,0.f,0.f};
    #pragma unroll
    for (int k=0;k<4;k++)
        #pragma unroll
        for (int mf=0; mf<4; mf++) accm[k][mf] = zz;

    bf16x8 pbv[4];
    dw_pass(xs, skernT, r0, cc, g, pbv);
    #pragma unroll
    for (int k=0;k<4;k++)
        #pragma unroll
        for (int mf=0; mf<4; mf++)
            accm[k][mf] = mfma16(afr[mf][0], pbv[k], accm[k][mf]);

    dw_pass(xs, skernT, r0, cc, 4+g, pbv);
    #pragma unroll
    for (int k=0;k<4;k++)
        #pragma unroll
        for (int mf=0; mf<4; mf++)
            accm[k][mf] = mfma16(afr[mf][1], pbv[k], accm[k][mf]);

    #pragma unroll
    for (int k=0;k<4;k++){
        int r = r0 + k;
        int h = h0 + r, w = w0 + cc;
        int spix = (r+1)*18 + (cc+1);
        int sw7 = spix & 7;
        #pragma unroll
        for (int mf=0; mf<4; mf++){
            int oc0 = mf*16 + g*4;
            f32x4 v = accm[k][mf];
            f32x4 cb4 = *(const f32x4*)&cb[oc0];
            f32x4 at4 = *(const f32x4*)&att[b*64 + oc0];
            int jg = (oc0 >> 3) ^ sw7;
            u16x4 xr = *(const u16x4*)&xs[spix*64 + jg*8 + (oc0 & 7)];
            u16x4 o;
            #pragma unroll
            for (int j=0; j<4; j++){
                float val = v[j] + cb4[j] + bf2f(xr[j])*at4[j];
                o[j] = f2bf(lk(val));
            }
            *(u16x4*)&outb[((size_t)(b*HW_ + h*W_ + w))*64 + oc0] = o;
        }
    }
}

// ---------------------------------------------------------------- launch
extern "C" void kernel_launch(void* const* d_in, const int* in_sizes, int n_in,
                              void* d_out, int out_size, void* d_ws, size_t ws_size,
                              hipStream_t stream)
{
    const float* x       = (const float*)d_in[0];
    const float* d       = (const float*)d_in[1];
    const float* da1_kw1 = (const float*)d_in[2];
    const float* da1_kw2 = (const float*)d_in[3];
    const float* da1_cw  = (const float*)d_in[4];
    const float* da1_cb  = (const float*)d_in[5];
    const float* da1_ca1 = (const float*)d_in[6];
    const float* da1_ca2 = (const float*)d_in[7];
    const float* da2_kw1 = (const float*)d_in[8];
    const float* da2_kw2 = (const float*)d_in[9];
    const float* da2_cw  = (const float*)d_in[10];
    const float* da2_cb  = (const float*)d_in[11];
    const float* da2_ca1 = (const float*)d_in[12];
    const float* da2_ca2 = (const float*)d_in[13];
    const float* conv1_w = (const float*)d_in[14];
    const float* conv1_b = (const float*)d_in[15];
    const float* conv2_w = (const float*)d_in[16];
    const float* conv2_b = (const float*)d_in[17];
    const float* conv3_w = (const float*)d_in[18];
    const float* conv3_b = (const float*)d_in[19];
    const float* add_w1  = (const float*)d_in[20];
    const float* add_w2  = (const float*)d_in[21];

    float* wsf   = (float*)d_ws;
    float* kern1 = wsf;
    float* att1  = wsf + 4608;
    float* kern2 = wsf + 5120;
    float* att2  = wsf + 9728;
    float* addm  = wsf + 10240;
    unsigned short* wsb  = (unsigned short*)(wsf + 18432);
    unsigned short* wA1  = wsb;
    unsigned short* wA2  = wA1 + 36864;
    unsigned short* wA3  = wA2 + 36864;
    unsigned short* cwA1 = wA3 + 36864;
    unsigned short* cwA2 = cwA1 + 4096;
    unsigned short* xbuf = cwA2 + 4096;
    const size_t N = (size_t)B_*HW_*64;
    unsigned short* buf0 = xbuf + N;
    unsigned short* buf1 = buf0 + N;
    unsigned short* zpage = buf1 + N;

    k_prep<<<1384, 256, 0, stream>>>(
        x, xbuf, d,
        da1_kw1, da1_kw2, da1_ca1, da1_ca2,
        da2_kw1, da2_kw2, da2_ca1, da2_ca2,
        add_w1, add_w2,
        kern1, att1, kern2, att2, addm,
        conv1_w, conv2_w, conv3_w, da1_cw, da2_cw,
        wA1, wA2, wA3, cwA1, cwA2, zpage);

    k_da<<<1152, 256, 0, stream>>>(xbuf, kern1, att1, cwA1, da1_cb, zpage, buf0);
    k_conv<0><<<1152, 256, 0, stream>>>(buf0, wA1, conv1_b, addm, zpage, buf1);
    k_conv<1><<<1152, 256, 0, stream>>>(buf1, wA2, conv2_b, nullptr, zpage, buf0);
    k_da<<<1152, 256, 0, stream>>>(buf0, kern2, att2, cwA2, da2_cb, zpage, buf1);
    kc3<<<1152, 256, 0, stream>>>(buf1, wA3, conv3_b, xbuf, zpage, (float*)d_out);

    (void)in_sizes; (void)n_in; (void)out_size; (void)ws_size;
}

// Round 16
// 245.679 us; speedup vs baseline: 1.0137x; 1.0137x over previous
//
#include <hip/hip_runtime.h>
#include <math.h>

#define B_ 8
#define C_ 64
#define H_ 192
#define W_ 192
#define HW_ (H_*W_)

typedef __attribute__((ext_vector_type(8))) short bf16x8;
typedef __attribute__((ext_vector_type(4))) float f32x4;
typedef __attribute__((ext_vector_type(4))) unsigned short u16x4;
typedef __attribute__((ext_vector_type(8))) unsigned short u16x8;
typedef __attribute__((ext_vector_type(4))) unsigned int u32x4;

__device__ __forceinline__ float lk(float v){ return v >= 0.f ? v : 0.1f*v; }
__device__ __forceinline__ float bf2f(unsigned short h){ return __uint_as_float(((unsigned)h)<<16); }
__device__ __forceinline__ unsigned short f2bf(float f){
    unsigned u = __float_as_uint(f);
    return (unsigned short)((u + 0x7fffu + ((u>>16)&1u)) >> 16);
}
__device__ __forceinline__ f32x4 mfma16(bf16x8 a, bf16x8 b, f32x4 c){
    return __builtin_amdgcn_mfma_f32_16x16x32_bf16(a, b, c, 0, 0, 0);
}

// XCD z-major decompose: L%8 = image = XCD; tiles sweep row-major within image.
__device__ __forceinline__ void xcd_decomp(int L, int& b, int& h0, int& w0){
    b = L & 7;
    int t = L >> 3;
    h0 = (t / 12) * 16;
    w0 = (t % 12) * 16;
}

// LDS staging pad: 11 full wave-rounds of 256 thr x 16B = 45056 B (2816 granules)
#define XS_ELEMS 22528
#define TSTRIDE 260   // xprep pivot row stride (u16): 520B row -> 2-dword bank step (free)

// ---------------------------------------------------------------- merged prep:
// blocks 0..1151  : x fp32 NCHW -> bf16 NHWC (coalesced+vectorized LDS pivot)
// blocks 1152..1159: per-image hypernet (kern/att/addm)
// blocks 1160..1383: weight repack + cw cast + zero page
__global__ __launch_bounds__(256) void k_prep(
    const float* __restrict__ xf, unsigned short* __restrict__ xb,
    const float* __restrict__ d,
    const float* __restrict__ kw1a, const float* __restrict__ kw2a,
    const float* __restrict__ ca1a, const float* __restrict__ ca2a,
    const float* __restrict__ kw1b, const float* __restrict__ kw2b,
    const float* __restrict__ ca1b, const float* __restrict__ ca2b,
    const float* __restrict__ aw1,  const float* __restrict__ aw2,
    float* __restrict__ kern1, float* __restrict__ att1,
    float* __restrict__ kern2, float* __restrict__ att2,
    float* __restrict__ addm,
    const float* __restrict__ w1, const float* __restrict__ w2, const float* __restrict__ w3,
    const float* __restrict__ cw1, const float* __restrict__ cw2,
    unsigned short* __restrict__ wA1, unsigned short* __restrict__ wA2, unsigned short* __restrict__ wA3,
    unsigned short* __restrict__ cwA1, unsigned short* __restrict__ cwA2,
    unsigned short* __restrict__ zp)
{
    int blk = blockIdx.x, tid = threadIdx.x;
    if (blk < 1152){
        // ---- xprep: wave-coalesced float4 reads (1KB/instr, one plane row) -> LDS -> NHWC stores
        int b = blk & 7, px0 = (blk >> 3)*256;
        __shared__ unsigned short ts[64*TSTRIDE];   // [c][px]
        int lane = tid & 63, wv = tid >> 6;
        #pragma unroll
        for (int it=0; it<16; it++){
            int c = wv*16 + it;
            f32x4 v = *(const f32x4*)(xf + ((size_t)(b*64 + c))*HW_ + px0 + lane*4);
            u16x4 o;
            #pragma unroll
            for (int j=0; j<4; j++) o[j] = f2bf(v[j]);
            *(u16x4*)&ts[c*TSTRIDE + lane*4] = o;
        }
        __syncthreads();
        int kg = tid & 7, pg = tid >> 3;
        #pragma unroll
        for (int jj=0; jj<8; jj++){
            int px = pg + 32*jj;
            u16x8 o;
            #pragma unroll
            for (int i=0; i<8; i++) o[i] = ts[(kg*8+i)*TSTRIDE + px];
            *(u16x8*)&xb[((size_t)(b*HW_) + px0 + px)*64 + kg*8] = o;
        }
    } else if (blk < 1160){
        // ---- hypernet for image b
        int b = blk - 1152;
        __shared__ float sd[64], sv[64], su[8];
        if (tid < 64) sd[tid] = d[b*64 + tid];
        __syncthreads();
        if (tid < 64){ float s=0.f; for(int k=0;k<64;k++) s += sd[k]*kw1a[tid*64+k]; sv[tid]=lk(s); }
        if (tid >= 64 && tid < 72){ int r=tid-64; float s=0.f; for(int k=0;k<64;k++) s += sd[k]*ca1a[r*64+k]; su[r]=lk(s); }
        __syncthreads();
        for (int i=tid;i<576;i+=256){ float s=0.f; for(int j=0;j<64;j++) s += sv[j]*kw2a[i*64+j]; kern1[b*576+i]=s; }
        if (tid < 64){ float s=0.f; for(int r=0;r<8;r++) s += su[r]*ca2a[tid*8+r]; att1[b*64+tid]=1.f/(1.f+expf(-s)); }
        __syncthreads();
        if (tid < 64){ float s=0.f; for(int k=0;k<64;k++) s += sd[k]*kw1b[tid*64+k]; sv[tid]=lk(s); }
        if (tid >= 64 && tid < 72){ int r=tid-64; float s=0.f; for(int k=0;k<64;k++) s += sd[k]*ca1b[r*64+k]; su[r]=lk(s); }
        __syncthreads();
        for (int i=tid;i<576;i+=256){ float s=0.f; for(int j=0;j<64;j++) s += sv[j]*kw2b[i*64+j]; kern2[b*576+i]=s; }
        if (tid < 64){ float s=0.f; for(int r=0;r<8;r++) s += su[r]*ca2b[tid*8+r]; att2[b*64+tid]=1.f/(1.f+expf(-s)); }
        __syncthreads();
        if (tid < 64){ float s=0.f; for(int k=0;k<64;k++) s += sd[k]*aw1[tid*64+k]; sv[tid]=lk(s); }
        __syncthreads();
        for (int i=tid;i<1024;i+=256){ float s=0.f; for(int j=0;j<64;j++) s += sv[j]*aw2[i*64+j]; addm[b*1024+i]=s; }
    } else {
        int pb = blk - 1160;
        if (pb < 192){
            const float* w = (pb < 64) ? w1 : (pb < 128) ? w2 : w3;
            unsigned short* wA = (pb < 64) ? wA1 : (pb < 128) ? wA2 : wA3;
            int oc = pb & 63;
            for (int i = tid; i < 576; i += 256){
                int t = i >> 6, ic = i & 63;
                wA[oc*576 + i] = f2bf(w[oc*576 + ic*9 + t]);
            }
        } else {
            int i = (pb - 192)*256 + tid;
            if (i < 4096) cwA1[i] = f2bf(cw1[i]);
            else          cwA2[i-4096] = f2bf(cw2[i-4096]);
            if (blk == 1383 && tid < 32) zp[tid] = 0;
        }
    }
}

// ---------------------------------------------------------------- DMA staging: linear LDS dest + pre-swizzled source
__device__ __forceinline__ void stage_gl(const unsigned short* __restrict__ in,
                                         unsigned short* xs,
                                         const unsigned short* __restrict__ zp,
                                         int b, int h0, int w0, int wv, int lane)
{
    #pragma unroll
    for (int i=0; i<11; i++){
        int e = i*256 + wv*64 + lane;
        int pix = e >> 3;
        int j = (e & 7) ^ (pix & 7);
        int r = pix/18, col = pix - r*18;
        int gh = h0 - 1 + r, gw = w0 - 1 + col;
        const unsigned short* src = (gh >= 0 && gh < H_ && gw >= 0 && gw < W_)
            ? &in[((size_t)(b*HW_ + gh*W_ + gw))*64 + j*8] : zp;
        __builtin_amdgcn_global_load_lds(
            (const __attribute__((address_space(1))) void*)src,
            (__attribute__((address_space(3))) void*)&xs[(size_t)(i*256 + wv*64)*8],
            16, 0, 0);
    }
}

// ---------------------------------------------------------------- main MFMA loop (R4/R8/R11-measured structure)
__device__ __forceinline__ void conv_main(const unsigned short* xs,
                                          const unsigned short* __restrict__ wbase,
                                          bf16x8 afr[2][2],
                                          int n, int g, int rowbase, f32x4 acc[2][8])
{
    #pragma unroll 1
    for (int t=0; t<9; t++){
        bf16x8 nxt[2][2];
        if (t < 8){
            #pragma unroll
            for (int mf=0; mf<2; mf++)
                #pragma unroll
                for (int kf=0; kf<2; kf++)
                    nxt[mf][kf] = *(const bf16x8*)(wbase + mf*(16*576) + (t+1)*64 + kf*32);
        }
        int dy = t/3, dx = t - dy*3;
        #pragma unroll
        for (int r=0; r<8; r++){
            int pix = (rowbase + r + dy)*18 + (n + dx);
            int sw = pix & 7;
            #pragma unroll
            for (int kf=0; kf<2; kf++){
                bf16x8 bfr = *(const bf16x8*)&xs[pix*64 + (((kf*4+g) ^ sw)*8)];
                acc[0][r] = mfma16(afr[0][kf], bfr, acc[0][r]);
                acc[1][r] = mfma16(afr[1][kf], bfr, acc[1][r]);
            }
        }
        if (t < 8){
            #pragma unroll
            for (int mf=0; mf<2; mf++)
                #pragma unroll
                for (int kf=0; kf<2; kf++) afr[mf][kf] = nxt[mf][kf];
        }
    }
}

// ---------------------------------------------------------------- conv stages 1/2 (bf16 NHWC out)
template<int MODE>
__global__ __launch_bounds__(256) void k_conv(
    const unsigned short* __restrict__ in,
    const unsigned short* __restrict__ wA,
    const float* __restrict__ bias,
    const float* __restrict__ addm,
    const unsigned short* __restrict__ zp,
    unsigned short* __restrict__ outb)
{
    int b, h0, w0; xcd_decomp(blockIdx.x, b, h0, w0);
    int tid = threadIdx.x;
    __shared__ unsigned short xs[XS_ELEMS];

    int lane = tid & 63, wv = tid >> 6;
    int n = lane & 15, g = lane >> 4;
    int ochalf = (wv & 1)*32, rowbase = (wv >> 1)*8;

    stage_gl(in, xs, zp, b, h0, w0, wv, lane);

    const unsigned short* wbase = wA + (size_t)(ochalf + n)*576 + g*8;
    bf16x8 afr[2][2];
    #pragma unroll
    for (int mf=0; mf<2; mf++)
        #pragma unroll
        for (int kf=0; kf<2; kf++)
            afr[mf][kf] = *(const bf16x8*)(wbase + mf*(16*576) + kf*32);

    __syncthreads();

    f32x4 acc[2][8];
    f32x4 zz = {0.f,0.f,0.f,0.f};
    #pragma unroll
    for (int mf=0; mf<2; mf++)
        #pragma unroll
        for (int r=0; r<8; r++) acc[mf][r] = zz;

    conv_main(xs, wbase, afr, n, g, rowbase, acc);

    #pragma unroll
    for (int r=0; r<8; r++){
        int h = h0 + rowbase + r, w = w0 + n;
        float addv = 0.f;
        if (MODE == 0) addv = addm[b*1024 + (h/6)*32 + (w/6)];
        #pragma unroll
        for (int mf=0; mf<2; mf++){
            int oc0 = ochalf + mf*16 + g*4;
            f32x4 v = acc[mf][r];
            f32x4 b4 = *(const f32x4*)&bias[oc0];
            u16x4 o;
            #pragma unroll
            for (int j=0;j<4;j++){
                float val = v[j] + b4[j];
                if (MODE == 0) val = lk(val) + addv;
                o[j] = f2bf(val);
            }
            *(u16x4*)&outb[((size_t)(b*HW_ + h*W_ + w))*64 + oc0] = o;
        }
    }
}

// ---------------------------------------------------------------- conv3: bf16 residual (prefetched), pivot epilogue
__global__ __launch_bounds__(256) void kc3(
    const unsigned short* __restrict__ in,
    const unsigned short* __restrict__ wA,
    const float* __restrict__ bias,
    const unsigned short* __restrict__ xresb,
    const unsigned short* __restrict__ zp,
    float* __restrict__ outf)
{
    int b, h0, w0; xcd_decomp(blockIdx.x, b, h0, w0);
    int tid = threadIdx.x;
    __shared__ unsigned short xs[XS_ELEMS];   // reused as ys[64][256] after compute

    int lane = tid & 63, wv = tid >> 6;
    int n = lane & 15, g = lane >> 4;
    int ochalf = (wv & 1)*32, rowbase = (wv >> 1)*8;

    stage_gl(in, xs, zp, b, h0, w0, wv, lane);

    const unsigned short* wbase = wA + (size_t)(ochalf + n)*576 + g*8;
    bf16x8 afr[2][2];
    #pragma unroll
    for (int mf=0; mf<2; mf++)
        #pragma unroll
        for (int kf=0; kf<2; kf++)
            afr[mf][kf] = *(const bf16x8*)(wbase + mf*(16*576) + kf*32);

    // prefetch residual (independent of LDS): flies under the barrier + conv
    u16x4 xr[2][4];
    u16x4 xr2[2][4];
    #pragma unroll
    for (int mf=0; mf<2; mf++){
        int oc0 = ochalf + mf*16 + g*4;
        #pragma unroll
        for (int r=0; r<4; r++){
            int h = h0 + rowbase + r, w = w0 + n;
            xr[mf][r] = *(const u16x4*)&xresb[((size_t)(b*HW_ + h*W_ + w))*64 + oc0];
        }
        #pragma unroll
        for (int r=4; r<8; r++){
            int h = h0 + rowbase + r, w = w0 + n;
            xr2[mf][r-4] = *(const u16x4*)&xresb[((size_t)(b*HW_ + h*W_ + w))*64 + oc0];
        }
    }

    __syncthreads();

    f32x4 acc[2][8];
    f32x4 zz = {0.f,0.f,0.f,0.f};
    #pragma unroll
    for (int mf=0; mf<2; mf++)
        #pragma unroll
        for (int r=0; r<8; r++) acc[mf][r] = zz;

    conv_main(xs, wbase, afr, n, g, rowbase, acc);

    __syncthreads();   // all xs reads done; reuse as ys
    unsigned short* ys = xs;

    #pragma unroll
    for (int mf=0; mf<2; mf++){
        int oc0 = ochalf + mf*16 + g*4;
        int sw = ((oc0 >> 2) & 3) << 2;
        f32x4 b4 = *(const f32x4*)&bias[oc0];
        #pragma unroll
        for (int r=0; r<8; r++){
            int px = (rowbase + r)*16 + n;
            u16x4 xv = (r < 4) ? xr[mf][r] : xr2[mf][r-4];
            f32x4 v = acc[mf][r];
            #pragma unroll
            for (int j=0; j<4; j++)
                ys[(oc0 + j)*256 + (px ^ sw)] = f2bf(v[j] + b4[j] + bf2f(xv[j]));
        }
    }
    __syncthreads();

    int q = lane & 3, rr = lane >> 2;
    #pragma unroll 1
    for (int pass=0; pass<16; pass++){
        int oc = wv + pass*4;
        int sw = ((oc >> 2) & 3) << 2;
        int px = (rr*16 + q*4) ^ sw;
        u16x4 t = *(const u16x4*)&ys[oc*256 + px];
        size_t gidx = ((size_t)(b*C_ + oc))*HW_ + (size_t)(h0 + rr)*W_ + w0 + q*4;
        f32x4 o;
        #pragma unroll
        for (int j=0; j<4; j++) o[j] = bf2f(t[j]);
        *(f32x4*)&outf[gidx] = o;
    }
}

// ---------------------------------------------------------------- depthwise pass: 4 output rows, one 8-ch granule
__device__ __forceinline__ void dw_pass(const unsigned short* xs, const float* skT,
                                        int r0, int cc, int gg, bf16x8 pbv[4])
{
    float acc[4][8];
    #pragma unroll
    for (int k=0;k<4;k++)
        #pragma unroll
        for (int i=0;i<8;i++) acc[k][i] = 0.f;

    #pragma unroll
    for (int ir=0; ir<6; ir++){
        float f[3][8];
        #pragma unroll
        for (int dx=0; dx<3; dx++){
            int spix = (r0+ir)*18 + cc + dx;
            bf16x8 v = *(const bf16x8*)&xs[spix*64 + ((gg ^ (spix&7))*8)];
            #pragma unroll
            for (int i=0;i<8;i++) f[dx][i] = bf2f((unsigned short)v[i]);
        }
        #pragma unroll
        for (int k=0;k<4;k++){
            if (ir >= k && ir <= k+2){
                int dy = ir - k;
                #pragma unroll
                for (int dx=0; dx<3; dx++){
                    f32x4 ka = *(const f32x4*)&skT[(dy*3+dx)*64 + gg*8];
                    f32x4 kb = *(const f32x4*)&skT[(dy*3+dx)*64 + gg*8 + 4];
                    #pragma unroll
                    for (int i=0;i<4;i++){
                        acc[k][i]   = fmaf(f[dx][i],   ka[i], acc[k][i]);
                        acc[k][i+4] = fmaf(f[dx][i+4], kb[i], acc[k][i+4]);
                    }
                }
            }
        }
    }
    #pragma unroll
    for (int k=0;k<4;k++){
        bf16x8 pb;
        #pragma unroll
        for (int i=0;i<8;i++) pb[i] = (short)f2bf(lk(acc[k][i]));
        pbv[k] = pb;
    }
}

// ---------------------------------------------------------------- da_conv: 16x16 tile, dw->regs->MFMA mix
__global__ __launch_bounds__(256) void k_da(
    const unsigned short* __restrict__ xb,
    const float* __restrict__ kern,
    const float* __restrict__ att,
    const unsigned short* __restrict__ cwA,
    const float* __restrict__ cb,
    const unsigned short* __restrict__ zp,
    unsigned short* __restrict__ outb)
{
    int b, h0, w0; xcd_decomp(blockIdx.x, b, h0, w0);
    int tid = threadIdx.x;
    __shared__ unsigned short xs[XS_ELEMS];
    __shared__ float skernT[576];

    int lane = tid & 63, wv = tid >> 6;
    int cc = lane & 15, g = lane >> 4;
    int r0 = wv*4;

    stage_gl(xb, xs, zp, b, h0, w0, wv, lane);

    for (int i = tid; i < 576; i += 256)
        skernT[i] = kern[b*576 + (i & 63)*9 + (i >> 6)];

    bf16x8 afr[4][2];
    #pragma unroll
    for (int mf=0; mf<4; mf++)
        #pragma unroll
        for (int kf=0; kf<2; kf++)
            afr[mf][kf] = *(const bf16x8*)&cwA[(size_t)(mf*16 + cc)*64 + kf*32 + g*8];

    __syncthreads();

    f32x4 accm[4][4];
    f32x4 zz = {0.f,0.f,0.f,0.f};
    #pragma unroll
    for (int k=0;k<4;k++)
        #pragma unroll
        for (int mf=0; mf<4; mf++) accm[k][mf] = zz;

    bf16x8 pbv[4];
    dw_pass(xs, skernT, r0, cc, g, pbv);
    #pragma unroll
    for (int k=0;k<4;k++)
        #pragma unroll
        for (int mf=0; mf<4; mf++)
            accm[k][mf] = mfma16(afr[mf][0], pbv[k], accm[k][mf]);

    dw_pass(xs, skernT, r0, cc, 4+g, pbv);
    #pragma unroll
    for (int k=0;k<4;k++)
        #pragma unroll
        for (int mf=0; mf<4; mf++)
            accm[k][mf] = mfma16(afr[mf][1], pbv[k], accm[k][mf]);

    #pragma unroll
    for (int k=0;k<4;k++){
        int r = r0 + k;
        int h = h0 + r, w = w0 + cc;
        int spix = (r+1)*18 + (cc+1);
        int sw7 = spix & 7;
        #pragma unroll
        for (int mf=0; mf<4; mf++){
            int oc0 = mf*16 + g*4;
            f32x4 v = accm[k][mf];
            f32x4 cb4 = *(const f32x4*)&cb[oc0];
            f32x4 at4 = *(const f32x4*)&att[b*64 + oc0];
            int jg = (oc0 >> 3) ^ sw7;
            u16x4 xr = *(const u16x4*)&xs[spix*64 + jg*8 + (oc0 & 7)];
            u16x4 o;
            #pragma unroll
            for (int j=0; j<4; j++){
                float val = v[j] + cb4[j] + bf2f(xr[j])*at4[j];
                o[j] = f2bf(lk(val));
            }
            *(u16x4*)&outb[((size_t)(b*HW_ + h*W_ + w))*64 + oc0] = o;
        }
    }
}

// ---------------------------------------------------------------- launch
extern "C" void kernel_launch(void* const* d_in, const int* in_sizes, int n_in,
                              void* d_out, int out_size, void* d_ws, size_t ws_size,
                              hipStream_t stream)
{
    const float* x       = (const float*)d_in[0];
    const float* d       = (const float*)d_in[1];
    const float* da1_kw1 = (const float*)d_in[2];
    const float* da1_kw2 = (const float*)d_in[3];
    const float* da1_cw  = (const float*)d_in[4];
    const float* da1_cb  = (const float*)d_in[5];
    const float* da1_ca1 = (const float*)d_in[6];
    const float* da1_ca2 = (const float*)d_in[7];
    const float* da2_kw1 = (const float*)d_in[8];
    const float* da2_kw2 = (const float*)d_in[9];
    const float* da2_cw  = (const float*)d_in[10];
    const float* da2_cb  = (const float*)d_in[11];
    const float* da2_ca1 = (const float*)d_in[12];
    const float* da2_ca2 = (const float*)d_in[13];
    const float* conv1_w = (const float*)d_in[14];
    const float* conv1_b = (const float*)d_in[15];
    const float* conv2_w = (const float*)d_in[16];
    const float* conv2_b = (const float*)d_in[17];
    const float* conv3_w = (const float*)d_in[18];
    const float* conv3_b = (const float*)d_in[19];
    const float* add_w1  = (const float*)d_in[20];
    const float* add_w2  = (const float*)d_in[21];

    float* wsf   = (float*)d_ws;
    float* kern1 = wsf;
    float* att1  = wsf + 4608;
    float* kern2 = wsf + 5120;
    float* att2  = wsf + 9728;
    float* addm  = wsf + 10240;
    unsigned short* wsb  = (unsigned short*)(wsf + 18432);
    unsigned short* wA1  = wsb;
    unsigned short* wA2  = wA1 + 36864;
    unsigned short* wA3  = wA2 + 36864;
    unsigned short* cwA1 = wA3 + 36864;
    unsigned short* cwA2 = cwA1 + 4096;
    unsigned short* xbuf = cwA2 + 4096;
    const size_t N = (size_t)B_*HW_*64;
    unsigned short* buf0 = xbuf + N;
    unsigned short* buf1 = buf0 + N;
    unsigned short* zpage = buf1 + N;

    k_prep<<<1384, 256, 0, stream>>>(
        x, xbuf, d,
        da1_kw1, da1_kw2, da1_ca1, da1_ca2,
        da2_kw1, da2_kw2, da2_ca1, da2_ca2,
        add_w1, add_w2,
        kern1, att1, kern2, att2, addm,
        conv1_w, conv2_w, conv3_w, da1_cw, da2_cw,
        wA1, wA2, wA3, cwA1, cwA2, zpage);

    k_da<<<1152, 256, 0, stream>>>(xbuf, kern1, att1, cwA1, da1_cb, zpage, buf0);
    k_conv<0><<<1152, 256, 0, stream>>>(buf0, wA1, conv1_b, addm, zpage, buf1);
    k_conv<1><<<1152, 256, 0, stream>>>(buf1, wA2, conv2_b, nullptr, zpage, buf0);
    k_da<<<1152, 256, 0, stream>>>(buf0, kern2, att2, cwA2, da2_cb, zpage, buf1);
    kc3<<<1152, 256, 0, stream>>>(buf1, wA3, conv3_b, xbuf, zpage, (float*)d_out);

    (void)in_sizes; (void)n_in; (void)out_size; (void)ws_size;
}